// Round 3
// baseline (829.837 us; speedup 1.0000x reference)
//
#include <hip/hip_runtime.h>
#include <hip/hip_fp16.h>
#include <math.h>

// RotationLayer: out = x + scatter_add over edges of rotated neighbor vectors.
//   t_u = R(+phase) @ x[u]  accumulated into out[v]
//   t_v = R(-phase) @ x[v]  accumulated into out[u]
//
// Round 7 == Round 6 resubmitted (round-6 bench died to an infra failure,
// no counters produced; source audit found no hang candidate).
//  - partition: round-5 regression was the compiler sinking the xh gathers
//    into the rotate loop (VGPR 52 < live set) -> serialized L2 latency.
//    Fix: sched_barrier(0) pins gather issue before the histogram; EPT 8->4
//    cuts LDS to ~22.5 KB -> ~6-7 blocks/CU for latency hiding;
//    launch_bounds(256,6) leaves VGPR room (~85). Record stores plain
//    (write-back combining); edge/phase loads stay nontemporal.
//  - accumulate: 1024-thread blocks (30 waves/CU, was 15) + unguarded
//    fast path for full 8-deep load batches.

#define NODE_SHIFT   11
#define BUCKET_NODES 2048
#define MAX_NB       512
#define PART_BLOCK   256
#define EPT          4                       // edges per thread (in registers)
#define EPB          (PART_BLOCK * EPT)      // 1024 edges per block
#define RPB          (2 * EPB)               // 2048 records per block

#define ACC_BLOCK    1024
#define ACC_UN       8                       // uint4 loads in flight per thread
#define FIX_SCALE    65536.0f
#define INV_FIX      (1.0f / 65536.0f)

typedef unsigned int uint;
typedef uint  uint4v  __attribute__((ext_vector_type(4)));
typedef uint  uint2v  __attribute__((ext_vector_type(2)));
typedef int   int4v   __attribute__((ext_vector_type(4)));
typedef float float2v __attribute__((ext_vector_type(2)));

static __device__ __forceinline__ uint pack_half2(float a, float b) {
    __half2 h = __floats2half2_rn(a, b);
    union { __half2 h2; uint u; } cvt; cvt.h2 = h; return cvt.u;
}

__global__ __launch_bounds__(256) void rot_make_xh(const float2* __restrict__ x2,
                                                   __half2* __restrict__ xh, int n) {
    int i = blockIdx.x * blockDim.x + threadIdx.x;
    if (i < n) {
        float2 v = x2[i];
        xh[i] = __floats2half2_rn(v.x, v.y);
    }
}

__global__ __launch_bounds__(256) void rot_zero_cursors(uint* __restrict__ cursors, int nb) {
    int i = blockIdx.x * blockDim.x + threadIdx.x;
    if (i < nb) cursors[i] = 0u;
}

__global__ __launch_bounds__(PART_BLOCK, 6) void rot_partition(
    const __half2* __restrict__ xh,
    const float*  __restrict__ phases,
    const int2*   __restrict__ edges,
    uint*  __restrict__ cursors,
    uint2* __restrict__ records,
    int e_begin, int e_end, int cap, int nbp)
{
    __shared__ uint2 s_rec[RPB];        // 16 KB sorted record staging
    __shared__ uint  s_cnt[MAX_NB];     // 2 KB
    __shared__ uint  s_excl[MAX_NB];    // 2 KB
    __shared__ uint  s_base[MAX_NB];    // 2 KB
    __shared__ uint  s_wsum[PART_BLOCK / 64];

    const int tid = threadIdx.x;
    const int block_e0 = e_begin + blockIdx.x * EPB;   // always even (e_chunk even)

    // ---- 1. Load EPT edges as int4 (2 edges/load) + phases as float2 ----
    int   eu[EPT], ev[EPT];
    float ph[EPT];
    uint  vmask = 0u;
    {
        const int4v*   e4 = (const int4v*)edges;       // int4 g covers edges 2g, 2g+1
        const float2v* p2 = (const float2v*)phases;
        #pragma unroll
        for (int i = 0; i < EPT / 2; ++i) {
            int g  = (block_e0 >> 1) + i * PART_BLOCK + tid;
            int e0 = 2 * g;
            int4v   q = {0, 0, 0, 0};
            float2v p = {0.f, 0.f};
            if (e0 < e_end) {                          // pair never straddles e_end (even)
                q = __builtin_nontemporal_load(&e4[g]);
                p = __builtin_nontemporal_load(&p2[g]);
            }
            int j0 = 2 * i, j1 = 2 * i + 1;
            eu[j0] = q.x; ev[j0] = q.y;
            eu[j1] = q.z; ev[j1] = q.w;
            ph[j0] = p.x; ph[j1] = p.y;
            if (e0     < e_end) vmask |= 1u << j0;
            if (e0 + 1 < e_end) vmask |= 1u << j1;
        }
    }
    // ---- 2. Issue all gathers NOW; sched_barrier pins them here so their
    //         latency hides under the histogram + scan. ----
    __half2 hu[EPT], hv[EPT];
    #pragma unroll
    for (int j = 0; j < EPT; ++j) {
        hu[j] = xh[eu[j]];
        hv[j] = xh[ev[j]];
    }
    __builtin_amdgcn_sched_barrier(0);

    // ---- 3. Histogram; the returned old value IS the local slot offset ----
    for (int b = tid; b < nbp; b += PART_BLOCK) s_cnt[b] = 0u;
    __syncthreads();

    uint metaU[EPT], metaV[EPT];
    #pragma unroll
    for (int j = 0; j < EPT; ++j) { metaU[j] = 0u; metaV[j] = 0u; }
    #pragma unroll
    for (int j = 0; j < EPT; ++j) {
        if ((vmask >> j) & 1u) {
            uint v  = (uint)ev[j];
            uint off = atomicAdd(&s_cnt[v >> NODE_SHIFT], 1u);
            metaV[j] = (off << 20) | v;                // off<=2047 (12b), v<2^20 (20b)
            uint u  = (uint)eu[j];
            off = atomicAdd(&s_cnt[u >> NODE_SHIFT], 1u);
            metaU[j] = (off << 20) | u;
        }
    }
    __syncthreads();

    // ---- 4. 2-barrier shuffle scan (each thread owns 2 buckets) ----
    {
        uint c0 = (2 * tid     < nbp) ? s_cnt[2 * tid]     : 0u;
        uint c1 = (2 * tid + 1 < nbp) ? s_cnt[2 * tid + 1] : 0u;
        uint sum = c0 + c1;
        uint incl = sum;
        #pragma unroll
        for (int d = 1; d < 64; d <<= 1) {
            uint o = __shfl_up(incl, (unsigned)d, 64);
            if ((tid & 63) >= d) incl += o;
        }
        int wv = tid >> 6;
        if ((tid & 63) == 63) s_wsum[wv] = incl;
        __syncthreads();
        uint wpref = 0;
        #pragma unroll
        for (int w = 0; w < PART_BLOCK / 64; ++w)
            if (w < wv) wpref += s_wsum[w];
        uint e0x = wpref + (incl - sum);               // exclusive prefix of bucket 2*tid
        if (2 * tid < nbp) {
            s_excl[2 * tid] = e0x;
            s_base[2 * tid] = c0 ? atomicAdd(&cursors[2 * tid], c0) : 0u;
        }
        if (2 * tid + 1 < nbp) {
            s_excl[2 * tid + 1] = e0x + c0;
            s_base[2 * tid + 1] = c1 ? atomicAdd(&cursors[2 * tid + 1], c1) : 0u;
        }
    }
    __syncthreads();

    // ---- 5. Compute rotations, place records sorted-by-bucket (no atomics) ----
    #pragma unroll
    for (int j = 0; j < EPT; ++j) {
        if ((vmask >> j) & 1u) {
            float s, c;
            __sincosf(ph[j], &s, &c);
            float2 fu = __half22float2(hu[j]);
            float2 fv = __half22float2(hv[j]);
            // contribution to out[v]: R(+p) @ x[u]
            float tux = fu.x * c - fu.y * s;
            float tuy = fu.x * s + fu.y * c;
            // contribution to out[u]: R(-p) @ x[v]
            float tvx = fv.x * c + fv.y * s;
            float tvy = fv.y * c - fv.x * s;
            {
                uint mv = metaV[j];
                uint v  = mv & 0xFFFFFu;
                uint b  = v >> NODE_SHIFT;
                uint slot = s_excl[b] + (mv >> 20);
                s_rec[slot] = make_uint2((b << 16) | (v & (BUCKET_NODES - 1)),
                                         pack_half2(tux, tuy));
            }
            {
                uint mu = metaU[j];
                uint u  = mu & 0xFFFFFu;
                uint b  = u >> NODE_SHIFT;
                uint slot = s_excl[b] + (mu >> 20);
                s_rec[slot] = make_uint2((b << 16) | (u & (BUCKET_NODES - 1)),
                                         pack_half2(tvx, tvy));
            }
        }
    }
    __syncthreads();

    // ---- 6. Coalesced flush (plain stores: write-back L2 combines runs) ----
    int valid_edges = e_end - block_e0;
    if (valid_edges > EPB) valid_edges = EPB;
    int total = 2 * valid_edges;
    for (int s = tid; s < total; s += PART_BLOCK) {
        uint2 r = s_rec[s];
        uint b = r.x >> 16;
        uint g = s_base[b] + ((uint)s - s_excl[b]);
        if (g < (uint)cap) records[(size_t)b * cap + g] = r;
    }
}

static __device__ __forceinline__ void acc_record(int* accX, int* accY, uint key, uint payload) {
    union { uint u; __half2 h; } cvt; cvt.u = payload;
    float2 f = __half22float2(cvt.h);
    uint node = key & 0xFFFFu;
    atomicAdd(&accX[node], __float2int_rn(f.x * FIX_SCALE));
    atomicAdd(&accY[node], __float2int_rn(f.y * FIX_SCALE));
}

__global__ __launch_bounds__(ACC_BLOCK) void rot_accumulate(
    const float2* __restrict__ x2,
    const uint*   __restrict__ cursors,
    const uint2*  __restrict__ records,
    float2* __restrict__ out2,
    int cap, int n_nodes, int first_chunk)
{
    __shared__ int accX[BUCKET_NODES];
    __shared__ int accY[BUCKET_NODES];
    for (int i = threadIdx.x; i < BUCKET_NODES; i += ACC_BLOCK) {
        accX[i] = 0; accY[i] = 0;
    }
    __syncthreads();

    const int b = blockIdx.x;
    uint cnt = cursors[b];
    if (cnt > (uint)cap) cnt = (uint)cap;
    const uint4v* rec4 = (const uint4v*)(records + (size_t)b * cap);
    uint n4 = cnt >> 1;                     // number of uint4 elements
    uint tid = threadIdx.x;

    const uint stride = (uint)(ACC_UN * ACC_BLOCK);
    uint nbat = (n4 + stride - 1) / stride;

    // Unguarded fast path: all but the last batch are full.
    for (uint bb = 0; bb + 1 < nbat; ++bb) {
        uint base = bb * stride + tid;
        uint4v r[ACC_UN];
        #pragma unroll
        for (int j = 0; j < ACC_UN; ++j)
            r[j] = __builtin_nontemporal_load(&rec4[base + (uint)j * ACC_BLOCK]);
        #pragma unroll
        for (int j = 0; j < ACC_UN; ++j) {
            acc_record(accX, accY, r[j].x, r[j].y);
            acc_record(accX, accY, r[j].z, r[j].w);
        }
    }
    // Guarded last batch.
    if (nbat) {
        uint base = (nbat - 1) * stride + tid;
        uint4v r[ACC_UN];
        #pragma unroll
        for (int j = 0; j < ACC_UN; ++j) {
            uint idx = base + (uint)j * ACC_BLOCK;
            uint4v z = {0, 0, 0, 0};
            r[j] = (idx < n4) ? __builtin_nontemporal_load(&rec4[idx]) : z;
        }
        #pragma unroll
        for (int j = 0; j < ACC_UN; ++j) {
            uint idx = base + (uint)j * ACC_BLOCK;
            if (idx < n4) {
                acc_record(accX, accY, r[j].x, r[j].y);
                acc_record(accX, accY, r[j].z, r[j].w);
            }
        }
    }
    if ((cnt & 1u) && tid == 0) {
        const uint2* rec = records + (size_t)b * cap;
        uint2 r = rec[cnt - 1];
        acc_record(accX, accY, r.x, r.y);
    }
    __syncthreads();

    const int node0 = b << NODE_SHIFT;
    for (int i = threadIdx.x; i < BUCKET_NODES; i += ACC_BLOCK) {
        int node = node0 + i;
        if (node < n_nodes) {
            float ax = (float)accX[i] * INV_FIX;
            float ay = (float)accY[i] * INV_FIX;
            float2 base = first_chunk ? x2[node] : out2[node];
            out2[node] = make_float2(base.x + ax, base.y + ay);
        }
    }
}

// ---------------- fallback (atomic path, used only if ws too small) ----------

__global__ __launch_bounds__(256) void rot_init_out(const float* __restrict__ x,
                                                    float* __restrict__ out, int n) {
    int i = blockIdx.x * blockDim.x + threadIdx.x;
    if (i < n) out[i] = x[i];
}

__global__ __launch_bounds__(256) void rot_edge_atomic(
    const float2* __restrict__ x2, const float* __restrict__ phases,
    const int2* __restrict__ edges, float* __restrict__ out, int n_edges)
{
    int e = blockIdx.x * blockDim.x + threadIdx.x;
    if (e >= n_edges) return;
    int2 uv = edges[e];
    float p = phases[e];
    float s = __sinf(p), c = __cosf(p);
    float2 hu = x2[uv.x], hv = x2[uv.y];
    unsafeAtomicAdd(&out[2 * uv.y + 0], hu.x * c - hu.y * s);
    unsafeAtomicAdd(&out[2 * uv.y + 1], hu.x * s + hu.y * c);
    unsafeAtomicAdd(&out[2 * uv.x + 0], hv.x * c + hv.y * s);
    unsafeAtomicAdd(&out[2 * uv.x + 1], hv.y * c - hv.x * s);
}

// -----------------------------------------------------------------------------

extern "C" void kernel_launch(void* const* d_in, const int* in_sizes, int n_in,
                              void* d_out, int out_size, void* d_ws, size_t ws_size,
                              hipStream_t stream) {
    const float* x      = (const float*)d_in[0];
    const float* phases = (const float*)d_in[1];
    const int2*  edges  = (const int2*)d_in[2];
    float* out = (float*)d_out;

    const int n_nodes = out_size / 2;
    const int E       = in_sizes[1];
    const int nb      = (n_nodes + BUCKET_NODES - 1) >> NODE_SHIFT;

    // Pick smallest chunk count k whose records + cursors + xh table fit in ws.
    int chosen_k = 0, chosen_cap = 0;
    if (d_ws && nb <= MAX_NB) {
        const int ks[5] = {1, 2, 4, 8, 16};
        for (int i = 0; i < 5; ++i) {
            int k = ks[i];
            long long e_chunk = ((long long)E + k - 1) / k;
            double m = (double)(2 * e_chunk) / (double)nb;
            long long cap = (long long)(m + 10.0 * sqrt(m) + 64.0);
            cap = (cap + 255) & ~255LL;
            long long need = (long long)nb * cap * 8       // records
                           + (((long long)nb * 4 + 255) & ~255LL)  // cursors
                           + (long long)n_nodes * 4 + 512;         // xh table
            if ((size_t)need <= ws_size) { chosen_k = k; chosen_cap = (int)cap; break; }
        }
    }

    if (chosen_k == 0) {
        rot_init_out<<<(out_size + 255) / 256, 256, 0, stream>>>(x, out, out_size);
        rot_edge_atomic<<<(E + 255) / 256, 256, 0, stream>>>(
            (const float2*)x, phases, edges, out, E);
        return;
    }

    const int cap = chosen_cap;
    uint2*   records = (uint2*)d_ws;
    size_t   off = (size_t)nb * cap * 8;
    uint*    cursors = (uint*)((char*)d_ws + off);
    off += ((size_t)nb * 4 + 255) & ~(size_t)255;
    __half2* xh = (__half2*)((char*)d_ws + off);

    // Build the 4 MB half2 gather table (fits per-XCD L2).
    rot_make_xh<<<(n_nodes + 255) / 256, 256, 0, stream>>>((const float2*)x, xh, n_nodes);

    int e_chunk = (E + chosen_k - 1) / chosen_k;
    e_chunk = (e_chunk + 1) & ~1;            // keep chunk boundaries even (int4 loads)
    for (int cidx = 0; cidx < chosen_k; ++cidx) {
        int e0 = cidx * e_chunk;
        int e1 = (e0 + e_chunk < E) ? (e0 + e_chunk) : E;
        if (e0 >= e1) break;

        rot_zero_cursors<<<(nb + 255) / 256, 256, 0, stream>>>(cursors, nb);

        int nblk = (e1 - e0 + EPB - 1) / EPB;
        rot_partition<<<nblk, PART_BLOCK, 0, stream>>>(
            xh, phases, edges, cursors, records, e0, e1, cap, nb);

        rot_accumulate<<<nb, ACC_BLOCK, 0, stream>>>(
            (const float2*)x, cursors, records, (float2*)out, cap, n_nodes,
            cidx == 0 ? 1 : 0);
    }
}

// Round 4
// 585.279 us; speedup vs baseline: 1.4178x; 1.4178x over previous
//
#include <hip/hip_runtime.h>
#include <hip/hip_fp16.h>
#include <math.h>

// RotationLayer: out = x + scatter_add over edges of rotated neighbor vectors.
//   t_u = R(+phase) @ x[u]  accumulated into out[v]
//   t_v = R(-phase) @ x[v]  accumulated into out[u]
//
// Round 8:
//  - partition: the xh gathers are now issued with global_load_lds (per-lane
//    global src -> wave-uniform LDS dest): an async HW gather that consumes
//    no result VGPRs, so the compiler CANNOT sink it into the rotate loop
//    (the round-5/round-7 failure mode, VGPR 52/36). Gathers fly during the
//    histogram (ds ops don't touch vmcnt); the pre-scan barrier drains them.
//    Gather region aliases s_rec's first 16 KB (values are copied to regs
//    before the scatter overwrites it) -> LDS 38.2 KB, 4 blocks/CU.
//  - EPT back to 8: ~8-record bucket runs halve record write amplification
//    (round-7's EPT=4 WRITE 488 MB -> ~390 MB).
//  - nontemporal on edges/phases loads AND record stores: keeps the 4 MB xh
//    table L2-resident (round-5 FETCH 220 MB vs round-7 plain-store 627 MB).
//  - accumulate: unchanged from round 7 (1024 thr, 8-deep batches, ~190 us).

#define NODE_SHIFT   11
#define BUCKET_NODES 2048
#define MAX_NB       512
#define PART_BLOCK   256
#define EPT          8                       // edges per thread (in registers)
#define EPB          (PART_BLOCK * EPT)      // 2048 edges per block
#define RPB          (2 * EPB)               // 4096 records per block

#define ACC_BLOCK    1024
#define ACC_UN       8                       // uint4 loads in flight per thread
#define FIX_SCALE    65536.0f
#define INV_FIX      (1.0f / 65536.0f)

typedef unsigned int uint;
typedef uint  uint4v  __attribute__((ext_vector_type(4)));
typedef uint  uint2v  __attribute__((ext_vector_type(2)));
typedef int   int4v   __attribute__((ext_vector_type(4)));
typedef float float2v __attribute__((ext_vector_type(2)));

static __device__ __forceinline__ uint pack_half2(float a, float b) {
    __half2 h = __floats2half2_rn(a, b);
    union { __half2 h2; uint u; } cvt; cvt.h2 = h; return cvt.u;
}

// Async 4-byte gather: per-lane global src, wave-uniform LDS base (+lane*4).
static __device__ __forceinline__ void gth4(const void* g, void* l) {
    __builtin_amdgcn_global_load_lds(
        (const __attribute__((address_space(1))) void*)g,
        (__attribute__((address_space(3))) void*)l, 4, 0, 0);
}

__global__ __launch_bounds__(256) void rot_make_xh(const float2* __restrict__ x2,
                                                   __half2* __restrict__ xh, int n) {
    int i = blockIdx.x * blockDim.x + threadIdx.x;
    if (i < n) {
        float2 v = x2[i];
        xh[i] = __floats2half2_rn(v.x, v.y);
    }
}

__global__ __launch_bounds__(256) void rot_zero_cursors(uint* __restrict__ cursors, int nb) {
    int i = blockIdx.x * blockDim.x + threadIdx.x;
    if (i < nb) cursors[i] = 0u;
}

__global__ __launch_bounds__(PART_BLOCK, 4) void rot_partition(
    const __half2* __restrict__ xh,
    const float*  __restrict__ phases,
    const int2*   __restrict__ edges,
    uint*  __restrict__ cursors,
    uint2* __restrict__ records,
    int e_begin, int e_end, int cap, int nbp)
{
    __shared__ uint2 s_rec[RPB];        // 32 KB; first 16 KB doubles as gather buf
    __shared__ uint  s_cnt[MAX_NB];     // 2 KB
    __shared__ uint  s_excl[MAX_NB];    // 2 KB
    __shared__ uint  s_base[MAX_NB];    // 2 KB
    __shared__ uint  s_wsum[PART_BLOCK / 64];

    uint* s_gth = (uint*)s_rec;         // 2*EPT*PART_BLOCK = 4096 uints = 16 KB

    const int tid = threadIdx.x;
    const int block_e0 = e_begin + blockIdx.x * EPB;   // always even (e_chunk even)

    // ---- A. Load EPT edges as int4 (2 edges/load) + phases as float2 ----
    int   eu[EPT], ev[EPT];
    float ph[EPT];
    uint  vmask = 0u;
    {
        const int4v*   e4 = (const int4v*)edges;       // int4 g covers edges 2g, 2g+1
        const float2v* p2 = (const float2v*)phases;
        #pragma unroll
        for (int i = 0; i < EPT / 2; ++i) {
            int g  = (block_e0 >> 1) + i * PART_BLOCK + tid;
            int e0 = 2 * g;
            int4v   q = {0, 0, 0, 0};
            float2v p = {0.f, 0.f};
            if (e0 < e_end) {                          // pair never straddles e_end (even)
                q = __builtin_nontemporal_load(&e4[g]);
                p = __builtin_nontemporal_load(&p2[g]);
            }
            int j0 = 2 * i, j1 = 2 * i + 1;
            eu[j0] = q.x; ev[j0] = q.y;
            eu[j1] = q.z; ev[j1] = q.w;
            ph[j0] = p.x; ph[j1] = p.y;
            if (e0     < e_end) vmask |= 1u << j0;
            if (e0 + 1 < e_end) vmask |= 1u << j1;
        }
    }

    // ---- B. Zero histogram bins (must precede atomics) ----
    for (int b = tid; b < nbp; b += PART_BLOCK) s_cnt[b] = 0u;
    __syncthreads();

    // ---- C. Issue all 16 async gathers; no result registers, not sinkable.
    //         They fly during the histogram (ds ops leave vmcnt alone). ----
    {
        const int wbase = tid & ~63;                   // wave-uniform LDS base
        #pragma unroll
        for (int j = 0; j < EPT; ++j) {
            gth4(&xh[eu[j]], &s_gth[(2 * j + 0) * PART_BLOCK + wbase]);
            gth4(&xh[ev[j]], &s_gth[(2 * j + 1) * PART_BLOCK + wbase]);
        }
    }
    __builtin_amdgcn_sched_barrier(0);

    // ---- D. Histogram; the returned old value IS the local slot offset ----
    uint metaU[EPT], metaV[EPT];
    #pragma unroll
    for (int j = 0; j < EPT; ++j) { metaU[j] = 0u; metaV[j] = 0u; }
    #pragma unroll
    for (int j = 0; j < EPT; ++j) {
        if ((vmask >> j) & 1u) {
            uint v  = (uint)ev[j];
            uint off = atomicAdd(&s_cnt[v >> NODE_SHIFT], 1u);
            metaV[j] = (off << 20) | v;                // off<=4095 (12b), v<2^20 (20b)
            uint u  = (uint)eu[j];
            off = atomicAdd(&s_cnt[u >> NODE_SHIFT], 1u);
            metaU[j] = (off << 20) | u;
        }
    }
    __syncthreads();                                    // drains gathers too

    // ---- E. 2-barrier shuffle scan (each thread owns 2 buckets) ----
    {
        uint c0 = (2 * tid     < nbp) ? s_cnt[2 * tid]     : 0u;
        uint c1 = (2 * tid + 1 < nbp) ? s_cnt[2 * tid + 1] : 0u;
        uint sum = c0 + c1;
        uint incl = sum;
        #pragma unroll
        for (int d = 1; d < 64; d <<= 1) {
            uint o = __shfl_up(incl, (unsigned)d, 64);
            if ((tid & 63) >= d) incl += o;
        }
        int wv = tid >> 6;
        if ((tid & 63) == 63) s_wsum[wv] = incl;
        __syncthreads();
        uint wpref = 0;
        #pragma unroll
        for (int w = 0; w < PART_BLOCK / 64; ++w)
            if (w < wv) wpref += s_wsum[w];
        uint e0x = wpref + (incl - sum);               // exclusive prefix of bucket 2*tid
        if (2 * tid < nbp) {
            s_excl[2 * tid] = e0x;
            s_base[2 * tid] = c0 ? atomicAdd(&cursors[2 * tid], c0) : 0u;
        }
        if (2 * tid + 1 < nbp) {
            s_excl[2 * tid + 1] = e0x + c0;
            s_base[2 * tid + 1] = c1 ? atomicAdd(&cursors[2 * tid + 1], c1) : 0u;
        }
    }
    __syncthreads();

    // ---- F. Copy gathered values to registers (region is about to be
    //         overwritten by the record scatter) ----
    uint gu[EPT], gv[EPT];
    #pragma unroll
    for (int j = 0; j < EPT; ++j) {
        gu[j] = s_gth[(2 * j + 0) * PART_BLOCK + tid];
        gv[j] = s_gth[(2 * j + 1) * PART_BLOCK + tid];
    }
    __syncthreads();

    // ---- G. Compute rotations, place records sorted-by-bucket (no atomics) ----
    #pragma unroll
    for (int j = 0; j < EPT; ++j) {
        if ((vmask >> j) & 1u) {
            float s, c;
            __sincosf(ph[j], &s, &c);
            union { uint u; __half2 h; } cu, cv;
            cu.u = gu[j]; cv.u = gv[j];
            float2 fu = __half22float2(cu.h);
            float2 fv = __half22float2(cv.h);
            // contribution to out[v]: R(+p) @ x[u]
            float tux = fu.x * c - fu.y * s;
            float tuy = fu.x * s + fu.y * c;
            // contribution to out[u]: R(-p) @ x[v]
            float tvx = fv.x * c + fv.y * s;
            float tvy = fv.y * c - fv.x * s;
            {
                uint mv = metaV[j];
                uint v  = mv & 0xFFFFFu;
                uint b  = v >> NODE_SHIFT;
                uint slot = s_excl[b] + (mv >> 20);
                s_rec[slot] = make_uint2((b << 16) | (v & (BUCKET_NODES - 1)),
                                         pack_half2(tux, tuy));
            }
            {
                uint mu = metaU[j];
                uint u  = mu & 0xFFFFFu;
                uint b  = u >> NODE_SHIFT;
                uint slot = s_excl[b] + (mu >> 20);
                s_rec[slot] = make_uint2((b << 16) | (u & (BUCKET_NODES - 1)),
                                         pack_half2(tvx, tvy));
            }
        }
    }
    __syncthreads();

    // ---- H. Coalesced flush (nontemporal: keep L2 for the xh table) ----
    int valid_edges = e_end - block_e0;
    if (valid_edges > EPB) valid_edges = EPB;
    int total = 2 * valid_edges;
    for (int s = tid; s < total; s += PART_BLOCK) {
        uint2 r = s_rec[s];
        uint b = r.x >> 16;
        uint g = s_base[b] + ((uint)s - s_excl[b]);
        if (g < (uint)cap) {
            uint2v rv = { r.x, r.y };
            __builtin_nontemporal_store(rv, (uint2v*)&records[(size_t)b * cap + g]);
        }
    }
}

static __device__ __forceinline__ void acc_record(int* accX, int* accY, uint key, uint payload) {
    union { uint u; __half2 h; } cvt; cvt.u = payload;
    float2 f = __half22float2(cvt.h);
    uint node = key & 0xFFFFu;
    atomicAdd(&accX[node], __float2int_rn(f.x * FIX_SCALE));
    atomicAdd(&accY[node], __float2int_rn(f.y * FIX_SCALE));
}

__global__ __launch_bounds__(ACC_BLOCK) void rot_accumulate(
    const float2* __restrict__ x2,
    const uint*   __restrict__ cursors,
    const uint2*  __restrict__ records,
    float2* __restrict__ out2,
    int cap, int n_nodes, int first_chunk)
{
    __shared__ int accX[BUCKET_NODES];
    __shared__ int accY[BUCKET_NODES];
    for (int i = threadIdx.x; i < BUCKET_NODES; i += ACC_BLOCK) {
        accX[i] = 0; accY[i] = 0;
    }
    __syncthreads();

    const int b = blockIdx.x;
    uint cnt = cursors[b];
    if (cnt > (uint)cap) cnt = (uint)cap;
    const uint4v* rec4 = (const uint4v*)(records + (size_t)b * cap);
    uint n4 = cnt >> 1;                     // number of uint4 elements
    uint tid = threadIdx.x;

    const uint stride = (uint)(ACC_UN * ACC_BLOCK);
    uint nbat = (n4 + stride - 1) / stride;

    // Unguarded fast path: all but the last batch are full.
    for (uint bb = 0; bb + 1 < nbat; ++bb) {
        uint base = bb * stride + tid;
        uint4v r[ACC_UN];
        #pragma unroll
        for (int j = 0; j < ACC_UN; ++j)
            r[j] = __builtin_nontemporal_load(&rec4[base + (uint)j * ACC_BLOCK]);
        #pragma unroll
        for (int j = 0; j < ACC_UN; ++j) {
            acc_record(accX, accY, r[j].x, r[j].y);
            acc_record(accX, accY, r[j].z, r[j].w);
        }
    }
    // Guarded last batch.
    if (nbat) {
        uint base = (nbat - 1) * stride + tid;
        uint4v r[ACC_UN];
        #pragma unroll
        for (int j = 0; j < ACC_UN; ++j) {
            uint idx = base + (uint)j * ACC_BLOCK;
            uint4v z = {0, 0, 0, 0};
            r[j] = (idx < n4) ? __builtin_nontemporal_load(&rec4[idx]) : z;
        }
        #pragma unroll
        for (int j = 0; j < ACC_UN; ++j) {
            uint idx = base + (uint)j * ACC_BLOCK;
            if (idx < n4) {
                acc_record(accX, accY, r[j].x, r[j].y);
                acc_record(accX, accY, r[j].z, r[j].w);
            }
        }
    }
    if ((cnt & 1u) && tid == 0) {
        const uint2* rec = records + (size_t)b * cap;
        uint2 r = rec[cnt - 1];
        acc_record(accX, accY, r.x, r.y);
    }
    __syncthreads();

    const int node0 = b << NODE_SHIFT;
    for (int i = threadIdx.x; i < BUCKET_NODES; i += ACC_BLOCK) {
        int node = node0 + i;
        if (node < n_nodes) {
            float ax = (float)accX[i] * INV_FIX;
            float ay = (float)accY[i] * INV_FIX;
            float2 base = first_chunk ? x2[node] : out2[node];
            out2[node] = make_float2(base.x + ax, base.y + ay);
        }
    }
}

// ---------------- fallback (atomic path, used only if ws too small) ----------

__global__ __launch_bounds__(256) void rot_init_out(const float* __restrict__ x,
                                                    float* __restrict__ out, int n) {
    int i = blockIdx.x * blockDim.x + threadIdx.x;
    if (i < n) out[i] = x[i];
}

__global__ __launch_bounds__(256) void rot_edge_atomic(
    const float2* __restrict__ x2, const float* __restrict__ phases,
    const int2* __restrict__ edges, float* __restrict__ out, int n_edges)
{
    int e = blockIdx.x * blockDim.x + threadIdx.x;
    if (e >= n_edges) return;
    int2 uv = edges[e];
    float p = phases[e];
    float s = __sinf(p), c = __cosf(p);
    float2 hu = x2[uv.x], hv = x2[uv.y];
    unsafeAtomicAdd(&out[2 * uv.y + 0], hu.x * c - hu.y * s);
    unsafeAtomicAdd(&out[2 * uv.y + 1], hu.x * s + hu.y * c);
    unsafeAtomicAdd(&out[2 * uv.x + 0], hv.x * c + hv.y * s);
    unsafeAtomicAdd(&out[2 * uv.x + 1], hv.y * c - hv.x * s);
}

// -----------------------------------------------------------------------------

extern "C" void kernel_launch(void* const* d_in, const int* in_sizes, int n_in,
                              void* d_out, int out_size, void* d_ws, size_t ws_size,
                              hipStream_t stream) {
    const float* x      = (const float*)d_in[0];
    const float* phases = (const float*)d_in[1];
    const int2*  edges  = (const int2*)d_in[2];
    float* out = (float*)d_out;

    const int n_nodes = out_size / 2;
    const int E       = in_sizes[1];
    const int nb      = (n_nodes + BUCKET_NODES - 1) >> NODE_SHIFT;

    // Pick smallest chunk count k whose records + cursors + xh table fit in ws.
    int chosen_k = 0, chosen_cap = 0;
    if (d_ws && nb <= MAX_NB) {
        const int ks[5] = {1, 2, 4, 8, 16};
        for (int i = 0; i < 5; ++i) {
            int k = ks[i];
            long long e_chunk = ((long long)E + k - 1) / k;
            double m = (double)(2 * e_chunk) / (double)nb;
            long long cap = (long long)(m + 10.0 * sqrt(m) + 64.0);
            cap = (cap + 255) & ~255LL;
            long long need = (long long)nb * cap * 8       // records
                           + (((long long)nb * 4 + 255) & ~255LL)  // cursors
                           + (long long)n_nodes * 4 + 512;         // xh table
            if ((size_t)need <= ws_size) { chosen_k = k; chosen_cap = (int)cap; break; }
        }
    }

    if (chosen_k == 0) {
        rot_init_out<<<(out_size + 255) / 256, 256, 0, stream>>>(x, out, out_size);
        rot_edge_atomic<<<(E + 255) / 256, 256, 0, stream>>>(
            (const float2*)x, phases, edges, out, E);
        return;
    }

    const int cap = chosen_cap;
    uint2*   records = (uint2*)d_ws;
    size_t   off = (size_t)nb * cap * 8;
    uint*    cursors = (uint*)((char*)d_ws + off);
    off += ((size_t)nb * 4 + 255) & ~(size_t)255;
    __half2* xh = (__half2*)((char*)d_ws + off);

    // Build the 4 MB half2 gather table (fits per-XCD L2).
    rot_make_xh<<<(n_nodes + 255) / 256, 256, 0, stream>>>((const float2*)x, xh, n_nodes);

    int e_chunk = (E + chosen_k - 1) / chosen_k;
    e_chunk = (e_chunk + 1) & ~1;            // keep chunk boundaries even (int4 loads)
    for (int cidx = 0; cidx < chosen_k; ++cidx) {
        int e0 = cidx * e_chunk;
        int e1 = (e0 + e_chunk < E) ? (e0 + e_chunk) : E;
        if (e0 >= e1) break;

        rot_zero_cursors<<<(nb + 255) / 256, 256, 0, stream>>>(cursors, nb);

        int nblk = (e1 - e0 + EPB - 1) / EPB;
        rot_partition<<<nblk, PART_BLOCK, 0, stream>>>(
            xh, phases, edges, cursors, records, e0, e1, cap, nb);

        rot_accumulate<<<nb, ACC_BLOCK, 0, stream>>>(
            (const float2*)x, cursors, records, (float2*)out, cap, n_nodes,
            cidx == 0 ? 1 : 0);
    }
}

// Round 5
// 505.765 us; speedup vs baseline: 1.6408x; 1.1572x over previous
//
#include <hip/hip_runtime.h>
#include <hip/hip_fp16.h>
#include <math.h>

// RotationLayer: out = x + scatter_add over edges of rotated neighbor vectors.
//   t_u = R(+phase) @ x[u]  accumulated into out[v]
//   t_v = R(-phase) @ x[v]  accumulated into out[u]
//
// Round 9:
//  THEORY: partition's ~350us floor (invariant across 3 rounds of gather /
//  atomic / occupancy changes) is the global cursor reservation: 489 hot
//  dwords x ~7813 serialized cross-XCD atomic RMWs each (~100cy) = ~325us.
//  FIX:
//   - cursors + record regions sharded 8-way by blockIdx&7 (~ XCD id on the
//     round-robin dispatch): per-address chain 7813 -> ~488, and each shard's
//     line tends to stay in one XCD's L2 (no ping-pong).
//   - 512-thread partition blocks (EPB 4096): halves block count.
//   - accumulate: 2 blocks per bucket (each consumes 4 of the 8 shards into
//     private LDS fixed-point accumulators) then unsafeAtomicAdd partials
//     into out (pre-initialized to x). 978 blocks vs 489 -> latency hiding.
//  Kept from prior rounds: global_load_lds async xh gathers (not sinkable),
//  nt loads for edges/phases + nt stores for records (xh stays L2-resident,
//  FETCH 224 MB), packed (off<<20|node) histogram-as-reservation.

#define NODE_SHIFT   11
#define BUCKET_NODES 2048
#define MAX_NB       512
#define PART_BLOCK   512
#define EPT          8                       // edges per thread (in registers)
#define EPB          (PART_BLOCK * EPT)      // 4096 edges per block
#define RPB          (2 * EPB)               // 8192 records per block

#define ACC_BLOCK    1024
#define FIX_SCALE    65536.0f
#define INV_FIX      (1.0f / 65536.0f)

typedef unsigned int uint;
typedef uint  uint4v  __attribute__((ext_vector_type(4)));
typedef uint  uint2v  __attribute__((ext_vector_type(2)));
typedef int   int4v   __attribute__((ext_vector_type(4)));
typedef float float2v __attribute__((ext_vector_type(2)));

static __device__ __forceinline__ uint pack_half2(float a, float b) {
    __half2 h = __floats2half2_rn(a, b);
    union { __half2 h2; uint u; } cvt; cvt.h2 = h; return cvt.u;
}

// Async 4-byte gather: per-lane global src, wave-uniform LDS base (+lane*4).
static __device__ __forceinline__ void gth4(const void* g, void* l) {
    __builtin_amdgcn_global_load_lds(
        (const __attribute__((address_space(1))) void*)g,
        (__attribute__((address_space(3))) void*)l, 4, 0, 0);
}

__global__ __launch_bounds__(256) void rot_make_xh(const float2* __restrict__ x2,
                                                   __half2* __restrict__ xh, int n) {
    int i = blockIdx.x * blockDim.x + threadIdx.x;
    if (i < n) {
        float2 v = x2[i];
        xh[i] = __floats2half2_rn(v.x, v.y);
    }
}

__global__ __launch_bounds__(256) void rot_zero_cursors(uint* __restrict__ cursors, int nc) {
    int i = blockIdx.x * blockDim.x + threadIdx.x;
    if (i < nc) cursors[i] = 0u;
}

__global__ __launch_bounds__(256) void rot_init_out(const float* __restrict__ x,
                                                    float* __restrict__ out, int n) {
    int i = blockIdx.x * blockDim.x + threadIdx.x;
    if (i < n) out[i] = x[i];
}

__global__ __launch_bounds__(PART_BLOCK, 4) void rot_partition(
    const __half2* __restrict__ xh,
    const float*  __restrict__ phases,
    const int2*   __restrict__ edges,
    uint*  __restrict__ cursors,      // [nb][nshard]
    uint2* __restrict__ records,      // [nb][nshard][cap8]
    int e_begin, int e_end, int cap8, int nbp, int nshard)
{
    __shared__ uint2 s_rec[RPB];        // 64 KB; first 32 KB doubles as gather buf
    __shared__ uint  s_cnt[MAX_NB];     // 2 KB
    __shared__ uint  s_excl[MAX_NB];    // 2 KB
    __shared__ uint  s_base[MAX_NB];    // 2 KB
    __shared__ uint  s_wsum[PART_BLOCK / 64];

    uint* s_gth = (uint*)s_rec;         // 2*EPT*PART_BLOCK = 8192 uints = 32 KB

    const int tid = threadIdx.x;
    const int shard = blockIdx.x & (nshard - 1);       // ~XCD id on MI355X
    const int block_e0 = e_begin + blockIdx.x * EPB;   // always even (e_chunk even)

    // ---- A. Load EPT edges as int4 (2 edges/load) + phases as float2 ----
    int   eu[EPT], ev[EPT];
    float ph[EPT];
    uint  vmask = 0u;
    {
        const int4v*   e4 = (const int4v*)edges;       // int4 g covers edges 2g, 2g+1
        const float2v* p2 = (const float2v*)phases;
        #pragma unroll
        for (int i = 0; i < EPT / 2; ++i) {
            int g  = (block_e0 >> 1) + i * PART_BLOCK + tid;
            int e0 = 2 * g;
            int4v   q = {0, 0, 0, 0};
            float2v p = {0.f, 0.f};
            if (e0 < e_end) {                          // pair never straddles e_end (even)
                q = __builtin_nontemporal_load(&e4[g]);
                p = __builtin_nontemporal_load(&p2[g]);
            }
            int j0 = 2 * i, j1 = 2 * i + 1;
            eu[j0] = q.x; ev[j0] = q.y;
            eu[j1] = q.z; ev[j1] = q.w;
            ph[j0] = p.x; ph[j1] = p.y;
            if (e0     < e_end) vmask |= 1u << j0;
            if (e0 + 1 < e_end) vmask |= 1u << j1;
        }
    }

    // ---- B. Zero histogram bins (must precede atomics) ----
    for (int b = tid; b < nbp; b += PART_BLOCK) s_cnt[b] = 0u;
    __syncthreads();

    // ---- C. Issue all 16 async gathers; no result registers, not sinkable.
    //         They fly during the histogram (ds ops leave vmcnt alone). ----
    {
        const int wbase = tid & ~63;                   // wave-uniform LDS base
        #pragma unroll
        for (int j = 0; j < EPT; ++j) {
            gth4(&xh[eu[j]], &s_gth[(2 * j + 0) * PART_BLOCK + wbase]);
            gth4(&xh[ev[j]], &s_gth[(2 * j + 1) * PART_BLOCK + wbase]);
        }
    }
    __builtin_amdgcn_sched_barrier(0);

    // ---- D. Histogram; the returned old value IS the local slot offset ----
    uint metaU[EPT], metaV[EPT];
    #pragma unroll
    for (int j = 0; j < EPT; ++j) { metaU[j] = 0u; metaV[j] = 0u; }
    #pragma unroll
    for (int j = 0; j < EPT; ++j) {
        if ((vmask >> j) & 1u) {
            uint v  = (uint)ev[j];
            uint off = atomicAdd(&s_cnt[v >> NODE_SHIFT], 1u);
            metaV[j] = (off << 20) | v;                // off<=4095 (12b), v<2^20 (20b)
            uint u  = (uint)eu[j];
            off = atomicAdd(&s_cnt[u >> NODE_SHIFT], 1u);
            metaU[j] = (off << 20) | u;
        }
    }
    __syncthreads();                                    // drains gathers too

    // ---- E. 1-bucket-per-thread shuffle scan + sharded global reservation ----
    {
        uint c = (tid < nbp) ? s_cnt[tid] : 0u;
        uint incl = c;
        #pragma unroll
        for (int d = 1; d < 64; d <<= 1) {
            uint o = __shfl_up(incl, (unsigned)d, 64);
            if ((tid & 63) >= d) incl += o;
        }
        int wv = tid >> 6;
        if ((tid & 63) == 63) s_wsum[wv] = incl;
        __syncthreads();
        uint wpref = 0;
        #pragma unroll
        for (int w = 0; w < PART_BLOCK / 64; ++w)
            if (w < wv) wpref += s_wsum[w];
        uint excl = wpref + (incl - c);                // exclusive prefix of bucket tid
        if (tid < nbp) {
            s_excl[tid] = excl;
            s_base[tid] = c ? atomicAdd(&cursors[tid * nshard + shard], c) : 0u;
        }
    }
    __syncthreads();

    // ---- F. Copy gathered values to registers (region is about to be
    //         overwritten by the record scatter) ----
    uint gu[EPT], gv[EPT];
    #pragma unroll
    for (int j = 0; j < EPT; ++j) {
        gu[j] = s_gth[(2 * j + 0) * PART_BLOCK + tid];
        gv[j] = s_gth[(2 * j + 1) * PART_BLOCK + tid];
    }
    __syncthreads();

    // ---- G. Compute rotations, place records sorted-by-bucket (no atomics) ----
    #pragma unroll
    for (int j = 0; j < EPT; ++j) {
        if ((vmask >> j) & 1u) {
            float s, c;
            __sincosf(ph[j], &s, &c);
            union { uint u; __half2 h; } cu, cv;
            cu.u = gu[j]; cv.u = gv[j];
            float2 fu = __half22float2(cu.h);
            float2 fv = __half22float2(cv.h);
            // contribution to out[v]: R(+p) @ x[u]
            float tux = fu.x * c - fu.y * s;
            float tuy = fu.x * s + fu.y * c;
            // contribution to out[u]: R(-p) @ x[v]
            float tvx = fv.x * c + fv.y * s;
            float tvy = fv.y * c - fv.x * s;
            {
                uint mv = metaV[j];
                uint v  = mv & 0xFFFFFu;
                uint b  = v >> NODE_SHIFT;
                uint slot = s_excl[b] + (mv >> 20);
                s_rec[slot] = make_uint2((b << 16) | (v & (BUCKET_NODES - 1)),
                                         pack_half2(tux, tuy));
            }
            {
                uint mu = metaU[j];
                uint u  = mu & 0xFFFFFu;
                uint b  = u >> NODE_SHIFT;
                uint slot = s_excl[b] + (mu >> 20);
                s_rec[slot] = make_uint2((b << 16) | (u & (BUCKET_NODES - 1)),
                                         pack_half2(tvx, tvy));
            }
        }
    }
    __syncthreads();

    // ---- H. Coalesced flush (nontemporal: keep L2 for the xh table) ----
    int valid_edges = e_end - block_e0;
    if (valid_edges > EPB) valid_edges = EPB;
    int total = 2 * valid_edges;
    for (int s = tid; s < total; s += PART_BLOCK) {
        uint2 r = s_rec[s];
        uint b = r.x >> 16;
        uint g = s_base[b] + ((uint)s - s_excl[b]);
        if (g < (uint)cap8) {
            uint2v rv = { r.x, r.y };
            __builtin_nontemporal_store(rv,
                (uint2v*)&records[((size_t)b * nshard + shard) * cap8 + g]);
        }
    }
}

static __device__ __forceinline__ void acc_record(int* accX, int* accY, uint key, uint payload) {
    union { uint u; __half2 h; } cvt; cvt.u = payload;
    float2 f = __half22float2(cvt.h);
    uint node = key & 0xFFFFu;
    atomicAdd(&accX[node], __float2int_rn(f.x * FIX_SCALE));
    atomicAdd(&accY[node], __float2int_rn(f.y * FIX_SCALE));
}

__global__ __launch_bounds__(ACC_BLOCK) void rot_accumulate(
    const uint*   __restrict__ cursors,   // [nb][nshard]
    const uint2*  __restrict__ records,   // [nb][nshard][cap8]
    float* __restrict__ out,              // pre-initialized to x
    int cap8, int n_nodes, int nshard, int split)
{
    __shared__ int accX[BUCKET_NODES];
    __shared__ int accY[BUCKET_NODES];
    for (int i = threadIdx.x; i < BUCKET_NODES; i += ACC_BLOCK) {
        accX[i] = 0; accY[i] = 0;
    }
    __syncthreads();

    const int bb  = blockIdx.x / split;
    const int h   = blockIdx.x - bb * split;
    const int spb = nshard / split;
    const uint tid = threadIdx.x;

    for (int s = h * spb; s < (h + 1) * spb; ++s) {
        uint cnt = cursors[bb * nshard + s];
        if (cnt > (uint)cap8) cnt = (uint)cap8;
        const uint2* rec = records + ((size_t)bb * nshard + s) * cap8;
        const uint4v* rec4 = (const uint4v*)rec;
        uint n4 = cnt >> 1;

        // 4-deep guarded batches (n4 per shard is small; keep loads in flight)
        for (uint i0 = tid; i0 < n4; i0 += 4u * ACC_BLOCK) {
            uint4v r[4];
            #pragma unroll
            for (int j = 0; j < 4; ++j) {
                uint idx = i0 + (uint)j * ACC_BLOCK;
                uint4v z = {0, 0, 0, 0};
                r[j] = (idx < n4) ? __builtin_nontemporal_load(&rec4[idx]) : z;
            }
            #pragma unroll
            for (int j = 0; j < 4; ++j) {
                uint idx = i0 + (uint)j * ACC_BLOCK;
                if (idx < n4) {
                    acc_record(accX, accY, r[j].x, r[j].y);
                    acc_record(accX, accY, r[j].z, r[j].w);
                }
            }
        }
        if ((cnt & 1u) && tid == 0) {
            uint2 r = rec[cnt - 1];
            acc_record(accX, accY, r.x, r.y);
        }
    }
    __syncthreads();

    const int node0 = bb << NODE_SHIFT;
    for (int i = threadIdx.x; i < BUCKET_NODES; i += ACC_BLOCK) {
        int node = node0 + i;
        if (node < n_nodes) {
            float ax = (float)accX[i] * INV_FIX;
            float ay = (float)accY[i] * INV_FIX;
            unsafeAtomicAdd(&out[2 * node + 0], ax);
            unsafeAtomicAdd(&out[2 * node + 1], ay);
        }
    }
}

// ---------------- fallback (atomic path, used only if ws too small) ----------

__global__ __launch_bounds__(256) void rot_edge_atomic(
    const float2* __restrict__ x2, const float* __restrict__ phases,
    const int2* __restrict__ edges, float* __restrict__ out, int n_edges)
{
    int e = blockIdx.x * blockDim.x + threadIdx.x;
    if (e >= n_edges) return;
    int2 uv = edges[e];
    float p = phases[e];
    float s = __sinf(p), c = __cosf(p);
    float2 hu = x2[uv.x], hv = x2[uv.y];
    unsafeAtomicAdd(&out[2 * uv.y + 0], hu.x * c - hu.y * s);
    unsafeAtomicAdd(&out[2 * uv.y + 1], hu.x * s + hu.y * c);
    unsafeAtomicAdd(&out[2 * uv.x + 0], hv.x * c + hv.y * s);
    unsafeAtomicAdd(&out[2 * uv.x + 1], hv.y * c - hv.x * s);
}

// -----------------------------------------------------------------------------

extern "C" void kernel_launch(void* const* d_in, const int* in_sizes, int n_in,
                              void* d_out, int out_size, void* d_ws, size_t ws_size,
                              hipStream_t stream) {
    const float* x      = (const float*)d_in[0];
    const float* phases = (const float*)d_in[1];
    const int2*  edges  = (const int2*)d_in[2];
    float* out = (float*)d_out;

    const int n_nodes = out_size / 2;
    const int E       = in_sizes[1];
    const int nb      = (n_nodes + BUCKET_NODES - 1) >> NODE_SHIFT;

    // Pick (chunks k, shards ns): smallest k, then most shards, that fits ws.
    int chosen_k = 0, chosen_ns = 0, chosen_cap = 0;
    if (d_ws && nb <= MAX_NB) {
        const int ks[5] = {1, 2, 4, 8, 16};
        const int nss[4] = {8, 4, 2, 1};
        for (int i = 0; i < 5 && !chosen_k; ++i) {
            int k = ks[i];
            for (int si = 0; si < 4 && !chosen_k; ++si) {
                int ns = nss[si];
                long long e_chunk = ((long long)E + k - 1) / k;
                double m = (double)(2 * e_chunk) / ((double)nb * ns);
                long long cap = (long long)(m + 10.0 * sqrt(m) + 64.0);
                cap = (cap + 63) & ~63LL;
                long long need = (long long)nb * ns * cap * 8          // records
                               + (((long long)nb * ns * 4 + 255) & ~255LL)  // cursors
                               + (long long)n_nodes * 4 + 512;              // xh table
                if ((size_t)need <= ws_size) {
                    chosen_k = k; chosen_ns = ns; chosen_cap = (int)cap;
                }
            }
        }
    }

    if (chosen_k == 0) {
        rot_init_out<<<(out_size + 255) / 256, 256, 0, stream>>>(x, out, out_size);
        rot_edge_atomic<<<(E + 255) / 256, 256, 0, stream>>>(
            (const float2*)x, phases, edges, out, E);
        return;
    }

    const int cap8 = chosen_cap;
    const int ns   = chosen_ns;
    uint2*   records = (uint2*)d_ws;
    size_t   off = (size_t)nb * ns * cap8 * 8;
    uint*    cursors = (uint*)((char*)d_ws + off);
    off += ((size_t)nb * ns * 4 + 255) & ~(size_t)255;
    __half2* xh = (__half2*)((char*)d_ws + off);

    // out = x (accumulate adds partials atomically), xh gather table (4 MB).
    rot_init_out<<<(out_size + 255) / 256, 256, 0, stream>>>(x, out, out_size);
    rot_make_xh<<<(n_nodes + 255) / 256, 256, 0, stream>>>((const float2*)x, xh, n_nodes);

    const int split = (ns >= 2) ? 2 : 1;
    int e_chunk = (E + chosen_k - 1) / chosen_k;
    e_chunk = (e_chunk + 1) & ~1;            // keep chunk boundaries even (int4 loads)
    for (int cidx = 0; cidx < chosen_k; ++cidx) {
        int e0 = cidx * e_chunk;
        int e1 = (e0 + e_chunk < E) ? (e0 + e_chunk) : E;
        if (e0 >= e1) break;

        rot_zero_cursors<<<(nb * ns + 255) / 256, 256, 0, stream>>>(cursors, nb * ns);

        int nblk = (e1 - e0 + EPB - 1) / EPB;
        rot_partition<<<nblk, PART_BLOCK, 0, stream>>>(
            xh, phases, edges, cursors, records, e0, e1, cap8, nb, ns);

        rot_accumulate<<<nb * split, ACC_BLOCK, 0, stream>>>(
            cursors, records, out, cap8, n_nodes, ns, split);
    }
}